// Round 15
// baseline (141.997 us; speedup 1.0000x reference)
//
#include <hip/hip_runtime.h>
#include <math.h>

// ---------------------------------------------------------------------------
// MultiScaleAdaptiveElasticityLossWithLame
// deformation_field: (2, 3, 160, 192, 160) f32
// image:             (2, 1, 160, 192, 160) f32
// out: scalar f32 = sum over 3 scales of mean(weight * elastic_energy)
//
// R15 = R14 (compile fix: loss_body takes B). Overlap instead of
// stall-fixing: K1 mega-kernel runs the scale-0 stream body on blocks
// [0,960) (19.6 KB LDS -> 8 blocks/CU, ~4 slots/CU spare) and churns the
// fused downsample for scales 1+2 through the spare slots CONCURRENTLY.
// K2 = fused gather-loss for scales 1+2. 6 launches -> 3.
// ---------------------------------------------------------------------------

#define LAMBDA_0 1.0f
#define MU_0 1.0f
#define KAPPA_LAMBDA 0.5f
#define KAPPA_MU 0.5f
#define BASE_WEIGHT 1.0f
#define GRADIENT_SCALING 0.1f

// ------------------- streaming-x LDS stencil (scale 0) ---------------------
constexpr int TY = 32;       // y tile
constexpr int TZ = 32;       // z tile (8 z-groups of 4)
constexpr int CX = 10;       // x planes per block
constexpr int PITCH = TZ + 4;        // 36 floats/row
constexpr int ROWS = TY + 2;         // 34 rows
constexpr int FSZ = ROWS * PITCH;    // 1224 floats per field

// problem geometry (compile-time)
constexpr int BATCH = 2;
constexpr int X0 = 160, Y0 = 192, Z0 = 160;
constexpr int X2 = 80, Y2 = 96, Z2 = 80;
constexpr int X4 = 40, Y4 = 48, Z4 = 40;
constexpr long long VOL2 = (long long)X2 * Y2 * Z2;   // 614400
constexpr long long VOL4 = (long long)X4 * Y4 * Z4;   // 76800

constexpr int NBY = Y0 / TY;                 // 6
constexpr int NBZ = Z0 / TZ;                 // 5
constexpr int NBX = X0 / CX;                 // 16
constexpr int N_STREAM = BATCH * NBY * NBZ * NBX;            // 960
constexpr int N_DS2 = (int)(8 * VOL2 / 256);                 // 19200
constexpr int N_DS4 = (int)(8 * VOL4 / 256);                 // 2400

struct P4 {
    float4 a, b, c, d;
    float ha, hb, hc, hd;
};

__device__ __forceinline__ P4 loadPlane(const float* __restrict__ p0,
                                        const float* __restrict__ p1,
                                        const float* __restrict__ p2,
                                        const float* __restrict__ p3,
                                        long long po, long long ctrOff,
                                        bool hasHalo, long long haloOff) {
    P4 r;
    long long o = po + ctrOff;
    r.a = *(const float4*)(p0 + o);
    r.b = *(const float4*)(p1 + o);
    r.c = *(const float4*)(p2 + o);
    r.d = *(const float4*)(p3 + o);
    r.ha = r.hb = r.hc = r.hd = 0.f;
    if (hasHalo) {
        long long h = po + haloOff;
        r.ha = p0[h]; r.hb = p1[h]; r.hc = p2[h]; r.hd = p3[h];
    }
    return r;
}

__device__ __forceinline__ void storePlane(float* lds, const P4& pr,
                                           int ldsCtr, bool hasHalo, int hIdx) {
    *(float4*)(lds + 0 * FSZ + ldsCtr) = pr.a;
    *(float4*)(lds + 1 * FSZ + ldsCtr) = pr.b;
    *(float4*)(lds + 2 * FSZ + ldsCtr) = pr.c;
    *(float4*)(lds + 3 * FSZ + ldsCtr) = pr.d;
    if (hasHalo) {
        lds[0 * FSZ + hIdx] = pr.ha;
        lds[1 * FSZ + hIdx] = pr.hb;
        lds[2 * FSZ + hIdx] = pr.hc;
        lds[3 * FSZ + hIdx] = pr.hd;
    }
}

__device__ __forceinline__ void unpackC(const P4& p, float d[4][4]) {
    d[0][0] = p.a.x; d[0][1] = p.a.y; d[0][2] = p.a.z; d[0][3] = p.a.w;
    d[1][0] = p.b.x; d[1][1] = p.b.y; d[1][2] = p.b.z; d[1][3] = p.b.w;
    d[2][0] = p.c.x; d[2][1] = p.c.y; d[2][2] = p.c.z; d[2][3] = p.c.w;
    d[3][0] = p.d.x; d[3][1] = p.d.y; d[3][2] = p.d.z; d[3][3] = p.d.w;
}

// ---- downsample body (R9's downsample_all8, z-innermost) -------------------
__device__ __forceinline__ void ds_body(const float* __restrict__ def,
                                        const float* __restrict__ img,
                                        float* __restrict__ odef,
                                        float* __restrict__ oimg,
                                        int inX, int inY, int inZ,
                                        int outX, int outY, int outZ,
                                        float rx, float ry, float rz,
                                        long long idx) {
    long long pervol = (long long)outX * outY * outZ;
    int m = (int)(idx / pervol);
    long long r = idx % pervol;
    int z = (int)(r % outZ);
    long long t = r / outZ;
    int y = (int)(t % outY);
    int x = (int)(t / outY);

    long long invol = (long long)inX * inY * inZ;
    const float* src;
    float* dst;
    if (m < 6) { src = def + (long long)m * invol;       dst = odef + (long long)m * pervol; }
    else       { src = img + (long long)(m - 6) * invol; dst = oimg + (long long)(m - 6) * pervol; }

    float cx = (float)x * rx;
    float cy = (float)y * ry;
    float cz = (float)z * rz;
    int ix0 = (int)floorf(cx), iy0 = (int)floorf(cy), iz0 = (int)floorf(cz);
    float wx = cx - (float)ix0, wy = cy - (float)iy0, wz = cz - (float)iz0;
    int ix1 = min(ix0 + 1, inX - 1);
    int iy1 = min(iy0 + 1, inY - 1);
    int iz1 = min(iz0 + 1, inZ - 1);

    long long sYZ = (long long)inY * inZ;
    long long bx0 = (long long)ix0 * sYZ, bx1 = (long long)ix1 * sYZ;
    long long by0 = (long long)iy0 * inZ, by1 = (long long)iy1 * inZ;

    float v000 = src[bx0 + by0 + iz0], v001 = src[bx0 + by0 + iz1];
    float v010 = src[bx0 + by1 + iz0], v011 = src[bx0 + by1 + iz1];
    float v100 = src[bx1 + by0 + iz0], v101 = src[bx1 + by0 + iz1];
    float v110 = src[bx1 + by1 + iz0], v111 = src[bx1 + by1 + iz1];

    float a00 = v000 * (1.f - wx) + v100 * wx;
    float a01 = v001 * (1.f - wx) + v101 * wx;
    float a10 = v010 * (1.f - wx) + v110 * wx;
    float a11 = v011 * (1.f - wx) + v111 * wx;
    float b0 = a00 * (1.f - wy) + a10 * wy;
    float b1 = a01 * (1.f - wy) + a11 * wy;
    dst[r] = b0 * (1.f - wz) + b1 * wz;
}

// ---- K1: mega kernel -------------------------------------------------------
__global__ void mega_stream_ds_kernel(const float* __restrict__ def,
                                      const float* __restrict__ img,
                                      float* __restrict__ def2,
                                      float* __restrict__ img2,
                                      float* __restrict__ def4,
                                      float* __restrict__ img4,
                                      float rx2, float ry2, float rz2,
                                      float rx4, float ry4, float rz4,
                                      float inv_n0,
                                      float* __restrict__ out) {
    __shared__ __align__(16) float lds[4 * FSZ];   // 19584 B -> 8 blocks/CU

    if (blockIdx.x >= N_STREAM) {
        // ---------------- downsample branch (fills stream stalls) ----------
        int db = blockIdx.x - N_STREAM;
        if (db < N_DS2) {
            long long idx = (long long)db * 256 + threadIdx.x;
            ds_body(def, img, def2, img2, X0, Y0, Z0, X2, Y2, Z2,
                    rx2, ry2, rz2, idx);
        } else {
            long long idx = (long long)(db - N_DS2) * 256 + threadIdx.x;
            ds_body(def, img, def4, img4, X0, Y0, Z0, X4, Y4, Z4,
                    rx4, ry4, rz4, idx);
        }
        return;
    }

    // ---------------- scale-0 stream body (R9/R3 verbatim) -----------------
    const int X = X0, Y = Y0, Z = Z0;
    int t = blockIdx.x;
    const int bx = t % NBX; t /= NBX;
    const int bz = t % NBZ; t /= NBZ;
    const int by = t % NBY; t /= NBY;
    const int b = t;

    const int tz = bz * TZ, ty = by * TY, x0 = bx * CX;
    const int tid = threadIdx.x;
    const int zg = tid & 7;    // 8 z-groups of 4
    const int ly = tid >> 3;   // 0..31

    const long long vol = (long long)X * Y * Z;
    const long long sX = (long long)Y * Z;
    const float* __restrict__ p0 = def + ((long long)b * 3 + 0) * vol;
    const float* __restrict__ p1 = def + ((long long)b * 3 + 1) * vol;
    const float* __restrict__ p2 = def + ((long long)b * 3 + 2) * vol;
    const float* __restrict__ p3 = img + (long long)b * vol;

    const int gy = ty + ly;
    const int gz0 = tz + 4 * zg;
    const long long ctrOff = (long long)gy * Z + gz0;
    const int ldsCtr = (ly + 1) * PITCH + 4 * zg;

    const bool hasHalo = (tid < 2 * (TZ + 2) + 2 * TY);   // 132
    int hIdx = 0;
    long long haloOff = 0;
    if (hasHalo) {
        int hr, hc;
        if (tid < TZ + 2)                { hr = 0;      hc = tid; }
        else if (tid < 2 * (TZ + 2))     { hr = TY + 1; hc = tid - (TZ + 2); }
        else if (tid < 2 * (TZ + 2) + TY){ hr = tid - 2 * (TZ + 2) + 1; hc = TZ; }
        else                             { hr = tid - (2 * (TZ + 2) + TY) + 1; hc = TZ + 1; }
        int zl = (hc < TZ) ? hc : ((hc == TZ) ? -1 : TZ);
        int hy = min(max(ty + hr - 1, 0), Y - 1);
        int hz = min(max(tz + zl, 0), Z - 1);
        haloOff = (long long)hy * Z + hz;
        hIdx = hr * PITCH + hc;
    }

    const bool ylo = (gy == 0), yhi = (gy == Y - 1);
    const bool zloE = (gz0 == 0), zhiE = (gz0 + 4 == Z);
    const int zmCol = (zg == 0) ? TZ : (4 * zg - 1);
    const int zpCol = (zg == 7) ? (TZ + 1) : (4 * zg + 4);
    const int rowM = ly * PITCH + 4 * zg;
    const int rowC = (ly + 1) * PITCH;
    const int rowP = (ly + 2) * PITCH + 4 * zg;

    float Cprev[4][4], Ccur[4][4], Cnext[4][4];
    {
        long long o = (long long)max(x0 - 1, 0) * sX + ctrOff;
        float4 a = *(const float4*)(p0 + o);
        float4 bq = *(const float4*)(p1 + o);
        float4 c = *(const float4*)(p2 + o);
        float4 d = *(const float4*)(p3 + o);
        Cprev[0][0]=a.x; Cprev[0][1]=a.y; Cprev[0][2]=a.z; Cprev[0][3]=a.w;
        Cprev[1][0]=bq.x;Cprev[1][1]=bq.y;Cprev[1][2]=bq.z;Cprev[1][3]=bq.w;
        Cprev[2][0]=c.x; Cprev[2][1]=c.y; Cprev[2][2]=c.z; Cprev[2][3]=c.w;
        Cprev[3][0]=d.x; Cprev[3][1]=d.y; Cprev[3][2]=d.z; Cprev[3][3]=d.w;
    }
    P4 cur = loadPlane(p0, p1, p2, p3, (long long)x0 * sX, ctrOff, hasHalo, haloOff);
    storePlane(lds, cur, ldsCtr, hasHalo, hIdx);
    unpackC(cur, Ccur);
    __syncthreads();
    P4 pn = loadPlane(p0, p1, p2, p3, (long long)(x0 + 1) * sX, ctrOff, hasHalo, haloOff);

    float acc = 0.f;
    for (int i = 0; i < CX; ++i) {
        const int x = x0 + i;
        const bool xlo = (x == 0), xhi = (x == X - 1);

        P4 q;
        const bool more = (i + 1 < CX);
        if (more) {
            long long xp = min(x + 2, X - 1);
            q = loadPlane(p0, p1, p2, p3, xp * sX, ctrOff, hasHalo, haloOff);
        }

        unpackC(pn, Cnext);

        float GX[4][4], GY[4][4], GZ[4][4];
#pragma unroll
        for (int f = 0; f < 4; ++f) {
            const float* L = lds + f * FSZ;
            float4 ym = *(const float4*)(L + rowM);
            float4 yp = *(const float4*)(L + rowP);
            float zm = L[rowC + zmCol];
            float zp = L[rowC + zpCol];
            float ymv[4] = {ym.x, ym.y, ym.z, ym.w};
            float ypv[4] = {yp.x, yp.y, yp.z, yp.w};
#pragma unroll
            for (int i2 = 0; i2 < 4; ++i2) {
                float C = Ccur[f][i2];
                GX[f][i2] = xlo ? (Cnext[f][i2] - C)
                                : (xhi ? (C - Cprev[f][i2])
                                       : 0.5f * (Cnext[f][i2] - Cprev[f][i2]));
                GY[f][i2] = ylo ? (ypv[i2] - C)
                                : (yhi ? (C - ymv[i2])
                                       : 0.5f * (ypv[i2] - ymv[i2]));
            }
            GZ[f][0] = zloE ? (Ccur[f][1] - Ccur[f][0]) : 0.5f * (Ccur[f][1] - zm);
            GZ[f][1] = 0.5f * (Ccur[f][2] - Ccur[f][0]);
            GZ[f][2] = 0.5f * (Ccur[f][3] - Ccur[f][1]);
            GZ[f][3] = zhiE ? (Ccur[f][3] - Ccur[f][2]) : 0.5f * (zp - Ccur[f][2]);
        }

#pragma unroll
        for (int i2 = 0; i2 < 4; ++i2) {
            float Exx = GX[0][i2], Eyy = GY[1][i2], Ezz = GZ[2][i2];
            float Exy = 0.5f * (GY[0][i2] + GX[1][i2]);
            float Exz = 0.5f * (GZ[0][i2] + GX[2][i2]);
            float Eyz = 0.5f * (GZ[1][i2] + GY[2][i2]);
            float tr = Exx + Eyy + Ezz;
            float g = sqrtf(GX[3][i2] * GX[3][i2] + GY[3][i2] * GY[3][i2] +
                            GZ[3][i2] * GZ[3][i2]);
            float lam = LAMBDA_0 + KAPPA_LAMBDA * g;
            float mu  = MU_0 + KAPPA_MU * g;
            float energy = 0.5f * lam * tr * tr +
                           mu * (Exx * Exx + Eyy * Eyy + Ezz * Ezz +
                                 2.0f * (Exy * Exy + Exz * Exz + Eyz * Eyz));
            float wgt = BASE_WEIGHT + GRADIENT_SCALING * g;
            acc += wgt * energy;
        }

        if (more) {
            __syncthreads();
            storePlane(lds, pn, ldsCtr, hasHalo, hIdx);
            __syncthreads();
#pragma unroll
            for (int f = 0; f < 4; ++f)
#pragma unroll
                for (int i2 = 0; i2 < 4; ++i2) {
                    Cprev[f][i2] = Ccur[f][i2];
                    Ccur[f][i2] = Cnext[f][i2];
                }
            pn = q;
        }
    }

    float val = acc * inv_n0;
    for (int off = 32; off > 0; off >>= 1)
        val += __shfl_down(val, off, 64);
    __shared__ float smem[4];
    int wid = (int)(threadIdx.x >> 6);
    if ((threadIdx.x & 63) == 0) smem[wid] = val;
    __syncthreads();
    if (threadIdx.x == 0) {
        atomicAdd(out, smem[0] + smem[1] + smem[2] + smem[3]);
    }
}

// ---- K2: fused gather loss for scales 1+2 ---------------------------------
__device__ __forceinline__ float loss_body(const float* __restrict__ def,
                                           const float* __restrict__ img,
                                           int B, int X, int Y, int Z,
                                           long long idx) {
    const int Zg = Z >> 2;
    int zg = (int)(idx % Zg);
    long long t = idx / Zg;
    int y = (int)(t % Y);
    t /= Y;
    int x = (int)(t % X);
    int b = (int)(t / X);
    (void)B;
    int z0 = zg << 2;

    long long vol = (long long)X * Y * Z;
    const float* base0 = def + ((long long)b * 3 + 0) * vol;
    const float* base1 = def + ((long long)b * 3 + 1) * vol;
    const float* base2 = def + ((long long)b * 3 + 2) * vol;
    const float* base3 = img + (long long)b * vol;
    const float* bases[4] = {base0, base1, base2, base3};

    long long sX = (long long)Y * Z;
    long long c = (long long)x * sX + (long long)y * Z + z0;
    long long cxm = (x > 0) ? c - sX : c;
    long long cxp = (x < X - 1) ? c + sX : c;
    long long cym = (y > 0) ? c - Z : c;
    long long cyp = (y < Y - 1) ? c + Z : c;
    long long czm = (z0 > 0) ? c - 1 : c;
    long long czp = (z0 + 4 < Z) ? c + 4 : c;

    float C[4][4], XM[4][4], XP[4][4], YM[4][4], YP[4][4];
    float ZM[4], ZP[4];
#pragma unroll
    for (int f = 0; f < 4; ++f) {
        const float* p = bases[f];
        float4 tc = *(const float4*)(p + c);
        float4 txm = *(const float4*)(p + cxm);
        float4 txp = *(const float4*)(p + cxp);
        float4 tym = *(const float4*)(p + cym);
        float4 typ = *(const float4*)(p + cyp);
        ZM[f] = p[czm];
        ZP[f] = p[czp];
        C[f][0] = tc.x;  C[f][1] = tc.y;  C[f][2] = tc.z;  C[f][3] = tc.w;
        XM[f][0] = txm.x; XM[f][1] = txm.y; XM[f][2] = txm.z; XM[f][3] = txm.w;
        XP[f][0] = txp.x; XP[f][1] = txp.y; XP[f][2] = txp.z; XP[f][3] = txp.w;
        YM[f][0] = tym.x; YM[f][1] = tym.y; YM[f][2] = tym.z; YM[f][3] = tym.w;
        YP[f][0] = typ.x; YP[f][1] = typ.y; YP[f][2] = typ.z; YP[f][3] = typ.w;
    }

    const bool xlo = (x == 0), xhi = (x == X - 1);
    const bool ylo = (y == 0), yhi = (y == Y - 1);
    const bool zlo = (z0 == 0), zhi = (z0 + 4 == Z);

    float GX[4][4], GY[4][4], GZ[4][4];
#pragma unroll
    for (int f = 0; f < 4; ++f) {
#pragma unroll
        for (int i = 0; i < 4; ++i) {
            GX[f][i] = xlo ? (XP[f][i] - C[f][i])
                           : (xhi ? (C[f][i] - XM[f][i])
                                  : 0.5f * (XP[f][i] - XM[f][i]));
            GY[f][i] = ylo ? (YP[f][i] - C[f][i])
                           : (yhi ? (C[f][i] - YM[f][i])
                                  : 0.5f * (YP[f][i] - YM[f][i]));
        }
        GZ[f][0] = zlo ? (C[f][1] - C[f][0]) : 0.5f * (C[f][1] - ZM[f]);
        GZ[f][1] = 0.5f * (C[f][2] - C[f][0]);
        GZ[f][2] = 0.5f * (C[f][3] - C[f][1]);
        GZ[f][3] = zhi ? (C[f][3] - C[f][2]) : 0.5f * (ZP[f] - C[f][2]);
    }

    float acc = 0.f;
#pragma unroll
    for (int i = 0; i < 4; ++i) {
        float Exx = GX[0][i], Eyy = GY[1][i], Ezz = GZ[2][i];
        float Exy = 0.5f * (GY[0][i] + GX[1][i]);
        float Exz = 0.5f * (GZ[0][i] + GX[2][i]);
        float Eyz = 0.5f * (GZ[1][i] + GY[2][i]);
        float tr = Exx + Eyy + Ezz;
        float g = sqrtf(GX[3][i] * GX[3][i] + GY[3][i] * GY[3][i] +
                        GZ[3][i] * GZ[3][i]);
        float lam = LAMBDA_0 + KAPPA_LAMBDA * g;
        float mu  = MU_0 + KAPPA_MU * g;
        float energy = 0.5f * lam * tr * tr +
                       mu * (Exx * Exx + Eyy * Eyy + Ezz * Ezz +
                             2.0f * (Exy * Exy + Exz * Exz + Eyz * Eyz));
        float wgt = BASE_WEIGHT + GRADIENT_SCALING * g;
        acc += wgt * energy;
    }
    return acc;
}

constexpr int G_LOSS2 = (int)(BATCH * VOL2 / 4 / 256);   // 1200
constexpr int G_LOSS4 = (int)(BATCH * VOL4 / 4 / 256);   // 150

__global__ void fused_loss_kernel(const float* __restrict__ def2,
                                  const float* __restrict__ img2,
                                  const float* __restrict__ def4,
                                  const float* __restrict__ img4,
                                  float inv_n2, float inv_n4,
                                  float* __restrict__ out) {
    float val;
    if (blockIdx.x < G_LOSS2) {
        long long idx = (long long)blockIdx.x * 256 + threadIdx.x;
        val = loss_body(def2, img2, BATCH, X2, Y2, Z2, idx) * inv_n2;
    } else {
        long long idx = (long long)(blockIdx.x - G_LOSS2) * 256 + threadIdx.x;
        val = loss_body(def4, img4, BATCH, X4, Y4, Z4, idx) * inv_n4;
    }

    for (int off = 32; off > 0; off >>= 1)
        val += __shfl_down(val, off, 64);
    __shared__ float smem[4];
    int wid = (int)(threadIdx.x >> 6);
    if ((threadIdx.x & 63) == 0) smem[wid] = val;
    __syncthreads();
    if (threadIdx.x == 0) {
        atomicAdd(out, smem[0] + smem[1] + smem[2] + smem[3]);
    }
}

extern "C" void kernel_launch(void* const* d_in, const int* in_sizes, int n_in,
                              void* d_out, int out_size, void* d_ws, size_t ws_size,
                              hipStream_t stream) {
    const float* def = (const float*)d_in[0];   // (2,3,160,192,160)
    const float* img = (const float*)d_in[1];   // (2,1,160,192,160)
    float* out = (float*)d_out;

    (void)hipMemsetAsync(out, 0, sizeof(float), stream);

    // workspace layout
    float* def2 = (float*)d_ws;
    float* img2 = def2 + (long long)BATCH * 3 * VOL2;
    float* def4 = img2 + (long long)BATCH * VOL2;
    float* img4 = def4 + (long long)BATCH * 3 * VOL4;

    const float rx2 = (float)((double)(X0 - 1) / (double)(X2 - 1));
    const float ry2 = (float)((double)(Y0 - 1) / (double)(Y2 - 1));
    const float rz2 = (float)((double)(Z0 - 1) / (double)(Z2 - 1));
    const float rx4 = (float)((double)(X0 - 1) / (double)(X4 - 1));
    const float ry4 = (float)((double)(Y0 - 1) / (double)(Y4 - 1));
    const float rz4 = (float)((double)(Z0 - 1) / (double)(Z4 - 1));

    const float inv_n0 = (float)(1.0 / (double)((long long)BATCH * X0 * Y0 * Z0));
    const float inv_n2 = (float)(1.0 / (double)(BATCH * VOL2));
    const float inv_n4 = (float)(1.0 / (double)(BATCH * VOL4));

    // K1: scale-0 stream (blocks 0..959) + downsample scales 1,2 (rest)
    {
        int grid = N_STREAM + N_DS2 + N_DS4;   // 960 + 19200 + 2400
        mega_stream_ds_kernel<<<grid, 256, 0, stream>>>(def, img,
                                                        def2, img2, def4, img4,
                                                        rx2, ry2, rz2,
                                                        rx4, ry4, rz4,
                                                        inv_n0, out);
    }

    // K2: fused gather loss for scales 1+2
    {
        int grid = G_LOSS2 + G_LOSS4;   // 1350
        fused_loss_kernel<<<grid, 256, 0, stream>>>(def2, img2, def4, img4,
                                                    inv_n2, inv_n4, out);
    }
}

// Round 16
// 139.956 us; speedup vs baseline: 1.0146x; 1.0146x over previous
//
#include <hip/hip_runtime.h>
#include <math.h>

// ---------------------------------------------------------------------------
// MultiScaleAdaptiveElasticityLossWithLame
// R16 scale-0: streaming-x stencil with __builtin_amdgcn_global_load_lds
// staging (m97 canonical pattern). 3 rotating LDS plane buffers; pitch-32
// tiles; XOR z-swizzle on the GLOBAL source (linear LDS dest, rule #21);
// y-halo rows via linear ds_write; z-halo via R6-proven conditional scalars;
// z+-1 via R10-proven lane shuffle. Tail: R9 verbatim (best measured).
// ---------------------------------------------------------------------------

#define LAMBDA_0 1.0f
#define MU_0 1.0f
#define KAPPA_LAMBDA 0.5f
#define KAPPA_MU 0.5f
#define BASE_WEIGHT 1.0f
#define GRADIENT_SCALING 0.1f

constexpr int TY = 32;       // y tile rows
constexpr int TZ = 32;       // z tile cols (8 groups of 4)
constexpr int CX = 10;       // x planes per block
// LDS layout per buffer (floats): 4 fields x [32r x 32z] + 256 halo floats
constexpr int FIELD_F = 1024;            // 32*32
constexpr int HALO_F  = 256;             // 4 fields x 2 rows x 32 z
constexpr int BUF_F   = 4 * FIELD_F + HALO_F;   // 4352 floats = 17408 B
constexpr int NBUF = 3;                  // 52224 B total -> 3 blocks/CU

__device__ __forceinline__ void gload_lds16(const float* g, float* l) {
    __builtin_amdgcn_global_load_lds(
        (const __attribute__((address_space(1))) unsigned int*)g,
        (__attribute__((address_space(3))) unsigned int*)l, 16, 0, 0);
}

// swizzled slot (float index within a buffer) for field f, row r (0..31),
// col-group c (0..7): matches the pre-swizzled global source below.
__device__ __forceinline__ int slotF(int f, int r, int c) {
    return f * FIELD_F + (r >> 3) * 256 + (r & 7) * 32 + ((c ^ (r & 7)) << 2);
}

__global__ void elasticity_stream_gld_kernel(const float* __restrict__ def,
                                             const float* __restrict__ img,
                                             int X, int Y, int Z,
                                             int nby, int nbz, int nbx,
                                             float inv_n,
                                             float* __restrict__ out) {
    __shared__ __align__(16) float lds[NBUF * BUF_F];

    int t0 = blockIdx.x;
    const int bx = t0 % nbx; t0 /= nbx;
    const int bz = t0 % nbz; t0 /= nbz;
    const int by = t0 % nby; t0 /= nby;
    const int b = t0;

    const int tz = bz * TZ, ty = by * TY, x0 = bx * CX;
    const int tid = threadIdx.x;
    const int zg = tid & 7;          // col-group 0..7
    const int ly = tid >> 3;         // row 0..31
    const int w = tid >> 6;          // wave 0..3 (uniform per wave)
    const int lyw = ly & 7;          // row within wave
    const int lane = tid & 63;
    const int laneM = (lane - 1) & 63;
    const int laneP = (lane + 1) & 63;

    const long long vol = (long long)X * Y * Z;
    const long long sX = (long long)Y * Z;
    const float* __restrict__ p0 = def + ((long long)b * 3 + 0) * vol;
    const float* __restrict__ p1 = def + ((long long)b * 3 + 1) * vol;
    const float* __restrict__ p2 = def + ((long long)b * 3 + 2) * vol;
    const float* __restrict__ p3 = img + (long long)b * vol;

    const int gy = ty + ly;
    const int gz0 = tz + 4 * zg;
    // pre-swizzled global source offset for the main-tile gload (rule #21):
    // this thread's LDS slot (lane*16) receives col-group (zg ^ lyw).
    const long long gldOff = (long long)gy * Z + tz + 4 * (zg ^ lyw);
    // halo loader: thread t covers field f=t>>6, row hr=(t>>5)&1, z hz=t&31
    const int hf = tid >> 6;             // uniform per wave
    const int hr = (tid >> 5) & 1;
    const int hz = tid & 31;
    const int hyRow = hr ? min(ty + TY, Y - 1) : max(ty - 1, 0);
    const long long haloGOff = (long long)hyRow * Z + tz + hz;
    const float* hp = (hf == 0) ? p0 : (hf == 1) ? p1 : (hf == 2) ? p2 : p3;

    const bool ylo = (gy == 0), yhi = (gy == Y - 1);
    const bool zloE = (gz0 == 0), zhiE = (gz0 + 4 == Z);
    const bool zem = (zg == 0), zep = (zg == 7);
    const long long ctrOff = (long long)gy * Z + gz0;
    const long long offZm = ctrOff - ((gz0 > 0) ? 1 : 0);
    const long long offZp = ctrOff + ((gz0 + 4 < Z) ? 4 : 3);

    // center slot indices (this thread's own row/col)
    const int sC  = slotF(0, ly, zg);        // field stride added per-field
    const int sYm = (ly > 0)  ? slotF(0, ly - 1, zg) : (4 * FIELD_F + 0 * 32 + 4 * zg);
    const int sYp = (ly < 31) ? slotF(0, ly + 1, zg) : (4 * FIELD_F + 32 + 4 * zg);
    // NOTE: halo region layout = [f][hr][hz]; per-field stride is 64 floats
    const int fldYm = (ly > 0)  ? FIELD_F : 64;   // stride per field for ym
    const int fldYp = (ly < 31) ? FIELD_F : 64;

    // issue main tile + halo for plane xq into buffer bi
    auto issue_plane = [&](int bi, int xq) {
        float* base = lds + bi * BUF_F;
        const long long po = (long long)xq * sX;
#pragma unroll
        for (int f = 0; f < 4; ++f) {
            const float* fp = (f == 0) ? p0 : (f == 1) ? p1 : (f == 2) ? p2 : p3;
            gload_lds16(fp + po + gldOff, base + f * FIELD_F + w * 256);
        }
        // halo row staging: one float per thread, linear ds_write
        base[4 * FIELD_F + ((hf * 2 + hr) * 32 + hz) - (hf * 64 + hr * 32 + hz) +
             (hf * 64 + hr * 32 + hz)] = hp[po + haloGOff];
    };

    // ---- prologue ----
    issue_plane(0, x0);
    issue_plane(1, min(x0 + 1, X - 1));

    float4 Cprev[4], Ccur[4], Cnext[4];
    {
        const long long po = (long long)max(x0 - 1, 0) * sX;
        Cprev[0] = *(const float4*)(p0 + po + ctrOff);
        Cprev[1] = *(const float4*)(p1 + po + ctrOff);
        Cprev[2] = *(const float4*)(p2 + po + ctrOff);
        Cprev[3] = *(const float4*)(p3 + po + ctrOff);
    }
    __syncthreads();   // drains vmcnt (gloads landed) + lgkm (halo writes)
    {
        const float* bb = lds;   // buffer 0
#pragma unroll
        for (int f = 0; f < 4; ++f)
            Ccur[f] = *(const float4*)(bb + f * FIELD_F + sC);
    }

    float acc = 0.f;
    for (int i = 0; i < CX; ++i) {
        const int x = x0 + i;
        const bool xlo = (x == 0), xhi = (x == X - 1);
        const bool more = (i + 1 < CX);
        const int b0 = i % 3, b1 = (i + 1) % 3, b2 = (i + 2) % 3;
        const float* B0 = lds + b0 * BUF_F;
        const float* B1 = lds + b1 * BUF_F;

        // 1) issue next-next plane into b2 (lands before it's read, 1 iter away)
        if (more) issue_plane(b2, min(x + 2, X - 1));

        // 2) z-halo scalars for the CURRENT plane (edge lanes only; R6-proven)
        float zmS[4] = {0.f, 0.f, 0.f, 0.f};
        float zpS[4] = {0.f, 0.f, 0.f, 0.f};
        {
            const long long po = (long long)x * sX;
            if (zem) {
                zmS[0] = p0[po + offZm]; zmS[1] = p1[po + offZm];
                zmS[2] = p2[po + offZm]; zmS[3] = p3[po + offZm];
            }
            if (zep) {
                zpS[0] = p0[po + offZp]; zpS[1] = p1[po + offZp];
                zpS[2] = p2[po + offZp]; zpS[3] = p3[po + offZp];
            }
        }

        // 3) LDS reads + gradients + energy
        float4 gx4[4], gy4[4], gz4[4];
#pragma unroll
        for (int f = 0; f < 4; ++f) {
            float4 cn = *(const float4*)(B1 + f * FIELD_F + sC);
            float4 ym = *(const float4*)(B0 + f * fldYm + sYm);
            float4 yp = *(const float4*)(B0 + f * fldYp + sYp);
            Cnext[f] = cn;
            float4 c = Ccur[f];
            float4 pv = Cprev[f];

            float4 gx, gyv, gz;
            gx.x = xlo ? (cn.x - c.x) : (xhi ? (c.x - pv.x) : 0.5f * (cn.x - pv.x));
            gx.y = xlo ? (cn.y - c.y) : (xhi ? (c.y - pv.y) : 0.5f * (cn.y - pv.y));
            gx.z = xlo ? (cn.z - c.z) : (xhi ? (c.z - pv.z) : 0.5f * (cn.z - pv.z));
            gx.w = xlo ? (cn.w - c.w) : (xhi ? (c.w - pv.w) : 0.5f * (cn.w - pv.w));

            gyv.x = ylo ? (yp.x - c.x) : (yhi ? (c.x - ym.x) : 0.5f * (yp.x - ym.x));
            gyv.y = ylo ? (yp.y - c.y) : (yhi ? (c.y - ym.y) : 0.5f * (yp.y - ym.y));
            gyv.z = ylo ? (yp.z - c.z) : (yhi ? (c.z - ym.z) : 0.5f * (yp.z - ym.z));
            gyv.w = ylo ? (yp.w - c.w) : (yhi ? (c.w - ym.w) : 0.5f * (yp.w - ym.w));

            float zmv = __shfl(c.w, laneM, 64);
            float zpv = __shfl(c.x, laneP, 64);
            float zm = zem ? zmS[f] : zmv;
            float zp = zep ? zpS[f] : zpv;
            gz.x = zloE ? (c.y - c.x) : 0.5f * (c.y - zm);
            gz.y = 0.5f * (c.z - c.x);
            gz.z = 0.5f * (c.w - c.y);
            gz.w = zhiE ? (c.w - c.z) : 0.5f * (zp - c.z);

            gx4[f] = gx; gy4[f] = gyv; gz4[f] = gz;
        }

#pragma unroll
        for (int j = 0; j < 4; ++j) {
            float Exx = (j == 0 ? gx4[0].x : j == 1 ? gx4[0].y : j == 2 ? gx4[0].z : gx4[0].w);
            float Eyy = (j == 0 ? gy4[1].x : j == 1 ? gy4[1].y : j == 2 ? gy4[1].z : gy4[1].w);
            float Ezz = (j == 0 ? gz4[2].x : j == 1 ? gz4[2].y : j == 2 ? gz4[2].z : gz4[2].w);
            float guy = (j == 0 ? gy4[0].x : j == 1 ? gy4[0].y : j == 2 ? gy4[0].z : gy4[0].w);
            float gvx = (j == 0 ? gx4[1].x : j == 1 ? gx4[1].y : j == 2 ? gx4[1].z : gx4[1].w);
            float guz = (j == 0 ? gz4[0].x : j == 1 ? gz4[0].y : j == 2 ? gz4[0].z : gz4[0].w);
            float gwx = (j == 0 ? gx4[2].x : j == 1 ? gx4[2].y : j == 2 ? gx4[2].z : gx4[2].w);
            float gvz = (j == 0 ? gz4[1].x : j == 1 ? gz4[1].y : j == 2 ? gz4[1].z : gz4[1].w);
            float gwy = (j == 0 ? gy4[2].x : j == 1 ? gy4[2].y : j == 2 ? gy4[2].z : gy4[2].w);
            float ix = (j == 0 ? gx4[3].x : j == 1 ? gx4[3].y : j == 2 ? gx4[3].z : gx4[3].w);
            float iy = (j == 0 ? gy4[3].x : j == 1 ? gy4[3].y : j == 2 ? gy4[3].z : gy4[3].w);
            float iz = (j == 0 ? gz4[3].x : j == 1 ? gz4[3].y : j == 2 ? gz4[3].z : gz4[3].w);

            float Exy = 0.5f * (guy + gvx);
            float Exz = 0.5f * (guz + gwx);
            float Eyz = 0.5f * (gvz + gwy);
            float tr = Exx + Eyy + Ezz;
            float g = sqrtf(ix * ix + iy * iy + iz * iz);
            float lam = LAMBDA_0 + KAPPA_LAMBDA * g;
            float mu  = MU_0 + KAPPA_MU * g;
            float energy = 0.5f * lam * tr * tr +
                           mu * (Exx * Exx + Eyy * Eyy + Ezz * Ezz +
                                 2.0f * (Exy * Exy + Exz * Exz + Eyz * Eyz));
            acc += (BASE_WEIGHT + GRADIENT_SCALING * g) * energy;
        }

        // 4) rotate; barrier closes plane (drains gloads for b2 + halo writes)
#pragma unroll
        for (int f = 0; f < 4; ++f) { Cprev[f] = Ccur[f]; Ccur[f] = Cnext[f]; }
        if (more) __syncthreads();
    }

    float val = acc * inv_n;
    for (int off = 32; off > 0; off >>= 1)
        val += __shfl_down(val, off, 64);
    __shared__ float smem[4];
    if ((tid & 63) == 0) smem[w] = val;
    __syncthreads();
    if (tid == 0)
        atomicAdd(out, smem[0] + smem[1] + smem[2] + smem[3]);
}

// --------- fused downsample: all 8 maps, z-innermost (R9 verbatim) ----------
__global__ void downsample_all8_kernel(const float* __restrict__ def,
                                       const float* __restrict__ img,
                                       float* __restrict__ odef,
                                       float* __restrict__ oimg,
                                       int inX, int inY, int inZ,
                                       int outX, int outY, int outZ,
                                       float rx, float ry, float rz) {
    long long pervol = (long long)outX * outY * outZ;
    long long total = 8LL * pervol;
    long long idx = (long long)blockIdx.x * blockDim.x + threadIdx.x;
    if (idx >= total) return;

    int m = (int)(idx / pervol);
    long long r = idx % pervol;
    int z = (int)(r % outZ);
    long long t = r / outZ;
    int y = (int)(t % outY);
    int x = (int)(t / outY);

    long long invol = (long long)inX * inY * inZ;
    const float* src;
    float* dst;
    if (m < 6) { src = def + (long long)m * invol;       dst = odef + (long long)m * pervol; }
    else       { src = img + (long long)(m - 6) * invol; dst = oimg + (long long)(m - 6) * pervol; }

    float cx = (float)x * rx;
    float cy = (float)y * ry;
    float cz = (float)z * rz;
    int ix0 = (int)floorf(cx), iy0 = (int)floorf(cy), iz0 = (int)floorf(cz);
    float wx = cx - (float)ix0, wy = cy - (float)iy0, wz = cz - (float)iz0;
    int ix1 = min(ix0 + 1, inX - 1);
    int iy1 = min(iy0 + 1, inY - 1);
    int iz1 = min(iz0 + 1, inZ - 1);

    long long sYZ = (long long)inY * inZ;
    long long bx0 = (long long)ix0 * sYZ, bx1 = (long long)ix1 * sYZ;
    long long by0 = (long long)iy0 * inZ, by1 = (long long)iy1 * inZ;

    float v000 = src[bx0 + by0 + iz0], v001 = src[bx0 + by0 + iz1];
    float v010 = src[bx0 + by1 + iz0], v011 = src[bx0 + by1 + iz1];
    float v100 = src[bx1 + by0 + iz0], v101 = src[bx1 + by0 + iz1];
    float v110 = src[bx1 + by1 + iz0], v111 = src[bx1 + by1 + iz1];

    float a00 = v000 * (1.f - wx) + v100 * wx;
    float a01 = v001 * (1.f - wx) + v101 * wx;
    float a10 = v010 * (1.f - wx) + v110 * wx;
    float a11 = v011 * (1.f - wx) + v111 * wx;
    float b0 = a00 * (1.f - wy) + a10 * wy;
    float b1 = a01 * (1.f - wy) + a11 * wy;
    dst[r] = b0 * (1.f - wz) + b1 * wz;
}

// ----------------- gather loss kernel (scales 1,2; R9 verbatim) -------------
__global__ void elasticity_loss_v4_kernel(const float* __restrict__ def,
                                          const float* __restrict__ img,
                                          int B, int X, int Y, int Z,
                                          float inv_n,
                                          float* __restrict__ out) {
    const int Zg = Z >> 2;
    long long total = (long long)B * X * Y * Zg;
    long long idx = (long long)blockIdx.x * blockDim.x + threadIdx.x;
    float val = 0.f;
    if (idx < total) {
        int zg = (int)(idx % Zg);
        long long t = idx / Zg;
        int y = (int)(t % Y);
        t /= Y;
        int x = (int)(t % X);
        int b = (int)(t / X);
        int z0 = zg << 2;

        long long vol = (long long)X * Y * Z;
        const float* base0 = def + ((long long)b * 3 + 0) * vol;
        const float* base1 = def + ((long long)b * 3 + 1) * vol;
        const float* base2 = def + ((long long)b * 3 + 2) * vol;
        const float* base3 = img + (long long)b * vol;
        const float* bases[4] = {base0, base1, base2, base3};

        long long sX = (long long)Y * Z;
        long long c = (long long)x * sX + (long long)y * Z + z0;
        long long cxm = (x > 0) ? c - sX : c;
        long long cxp = (x < X - 1) ? c + sX : c;
        long long cym = (y > 0) ? c - Z : c;
        long long cyp = (y < Y - 1) ? c + Z : c;
        long long czm = (z0 > 0) ? c - 1 : c;
        long long czp = (z0 + 4 < Z) ? c + 4 : c;

        float C[4][4], XM[4][4], XP[4][4], YM[4][4], YP[4][4];
        float ZM[4], ZP[4];
#pragma unroll
        for (int f = 0; f < 4; ++f) {
            const float* p = bases[f];
            float4 tc = *(const float4*)(p + c);
            float4 txm = *(const float4*)(p + cxm);
            float4 txp = *(const float4*)(p + cxp);
            float4 tym = *(const float4*)(p + cym);
            float4 typ = *(const float4*)(p + cyp);
            ZM[f] = p[czm];
            ZP[f] = p[czp];
            C[f][0] = tc.x;  C[f][1] = tc.y;  C[f][2] = tc.z;  C[f][3] = tc.w;
            XM[f][0] = txm.x; XM[f][1] = txm.y; XM[f][2] = txm.z; XM[f][3] = txm.w;
            XP[f][0] = txp.x; XP[f][1] = txp.y; XP[f][2] = txp.z; XP[f][3] = txp.w;
            YM[f][0] = tym.x; YM[f][1] = tym.y; YM[f][2] = tym.z; YM[f][3] = tym.w;
            YP[f][0] = typ.x; YP[f][1] = typ.y; YP[f][2] = typ.z; YP[f][3] = typ.w;
        }

        const bool xlo = (x == 0), xhi = (x == X - 1);
        const bool ylo = (y == 0), yhi = (y == Y - 1);
        const bool zlo = (z0 == 0), zhi = (z0 + 4 == Z);

        float GX[4][4], GY[4][4], GZ[4][4];
#pragma unroll
        for (int f = 0; f < 4; ++f) {
#pragma unroll
            for (int i = 0; i < 4; ++i) {
                GX[f][i] = xlo ? (XP[f][i] - C[f][i])
                               : (xhi ? (C[f][i] - XM[f][i])
                                      : 0.5f * (XP[f][i] - XM[f][i]));
                GY[f][i] = ylo ? (YP[f][i] - C[f][i])
                               : (yhi ? (C[f][i] - YM[f][i])
                                      : 0.5f * (YP[f][i] - YM[f][i]));
            }
            GZ[f][0] = zlo ? (C[f][1] - C[f][0]) : 0.5f * (C[f][1] - ZM[f]);
            GZ[f][1] = 0.5f * (C[f][2] - C[f][0]);
            GZ[f][2] = 0.5f * (C[f][3] - C[f][1]);
            GZ[f][3] = zhi ? (C[f][3] - C[f][2]) : 0.5f * (ZP[f] - C[f][2]);
        }

        float acc = 0.f;
#pragma unroll
        for (int i = 0; i < 4; ++i) {
            float Exx = GX[0][i], Eyy = GY[1][i], Ezz = GZ[2][i];
            float Exy = 0.5f * (GY[0][i] + GX[1][i]);
            float Exz = 0.5f * (GZ[0][i] + GX[2][i]);
            float Eyz = 0.5f * (GZ[1][i] + GY[2][i]);
            float tr = Exx + Eyy + Ezz;
            float g = sqrtf(GX[3][i] * GX[3][i] + GY[3][i] * GY[3][i] +
                            GZ[3][i] * GZ[3][i]);
            float lam = LAMBDA_0 + KAPPA_LAMBDA * g;
            float mu  = MU_0 + KAPPA_MU * g;
            float energy = 0.5f * lam * tr * tr +
                           mu * (Exx * Exx + Eyy * Eyy + Ezz * Ezz +
                                 2.0f * (Exy * Exy + Exz * Exz + Eyz * Eyz));
            float wgt = BASE_WEIGHT + GRADIENT_SCALING * g;
            acc += wgt * energy;
        }
        val = acc * inv_n;
    }

    for (int off = 32; off > 0; off >>= 1)
        val += __shfl_down(val, off, 64);
    __shared__ float smem[8];
    int lane = threadIdx.x & 63;
    int wid = (int)(threadIdx.x >> 6);
    if (lane == 0) smem[wid] = val;
    __syncthreads();
    if (threadIdx.x == 0) {
        float s = 0.f;
        int nw = (int)(blockDim.x >> 6);
        for (int i = 0; i < nw; ++i) s += smem[i];
        atomicAdd(out, s);
    }
}

static void launch_loss_v4(const float* def, const float* img, int B, int X,
                           int Y, int Z, float* out, hipStream_t stream) {
    const int BLOCK = 256;
    long long nvox = (long long)B * X * Y * Z;
    long long total = nvox >> 2;
    float inv_n = (float)(1.0 / (double)nvox);
    int grid = (int)((total + BLOCK - 1) / BLOCK);
    elasticity_loss_v4_kernel<<<grid, BLOCK, 0, stream>>>(def, img, B, X, Y, Z,
                                                          inv_n, out);
}

extern "C" void kernel_launch(void* const* d_in, const int* in_sizes, int n_in,
                              void* d_out, int out_size, void* d_ws, size_t ws_size,
                              hipStream_t stream) {
    const float* def = (const float*)d_in[0];   // (2,3,160,192,160)
    const float* img = (const float*)d_in[1];   // (2,1,160,192,160)
    float* out = (float*)d_out;

    const int B = 2;
    const int X0 = 160, Y0 = 192, Z0 = 160;

    (void)hipMemsetAsync(out, 0, sizeof(float), stream);

    const int BLOCK = 256;

    // ---------------- scale 0: global_load_lds streaming stencil ------------
    {
        long long nvox = (long long)B * X0 * Y0 * Z0;
        float inv_n = (float)(1.0 / (double)nvox);
        int nby = Y0 / TY;   // 6
        int nbz = Z0 / TZ;   // 5
        int nbx = X0 / CX;   // 16
        int grid = B * nby * nbz * nbx;   // 960
        elasticity_stream_gld_kernel<<<grid, 256, 0, stream>>>(def, img,
                                                               X0, Y0, Z0,
                                                               nby, nbz, nbx,
                                                               inv_n, out);
    }

    // workspace layout
    const int X2 = 80, Y2 = 96, Z2 = 80;
    const int X4 = 40, Y4 = 48, Z4 = 40;
    long long vol2 = (long long)X2 * Y2 * Z2;
    long long vol4 = (long long)X4 * Y4 * Z4;

    float* def2 = (float*)d_ws;
    float* img2 = def2 + (long long)B * 3 * vol2;
    float* def4 = img2 + (long long)B * vol2;
    float* img4 = def4 + (long long)B * 3 * vol4;

    // ---------------- scale 1 (x2 downsample, fused all-8-maps) -------------
    {
        float rx = (float)((double)(X0 - 1) / (double)(X2 - 1));
        float ry = (float)((double)(Y0 - 1) / (double)(Y2 - 1));
        float rz = (float)((double)(Z0 - 1) / (double)(Z2 - 1));
        long long total = 8LL * vol2;
        int g = (int)((total + BLOCK - 1) / BLOCK);
        downsample_all8_kernel<<<g, BLOCK, 0, stream>>>(def, img, def2, img2,
                                                        X0, Y0, Z0, X2, Y2, Z2,
                                                        rx, ry, rz);
        launch_loss_v4(def2, img2, B, X2, Y2, Z2, out, stream);
    }

    // ---------------- scale 2 (x4 downsample, from original) ----------------
    {
        float rx = (float)((double)(X0 - 1) / (double)(X4 - 1));
        float ry = (float)((double)(Y0 - 1) / (double)(Y4 - 1));
        float rz = (float)((double)(Z0 - 1) / (double)(Z4 - 1));
        long long total = 8LL * vol4;
        int g = (int)((total + BLOCK - 1) / BLOCK);
        downsample_all8_kernel<<<g, BLOCK, 0, stream>>>(def, img, def4, img4,
                                                        X0, Y0, Z0, X4, Y4, Z4,
                                                        rx, ry, rz);
        launch_loss_v4(def4, img4, B, X4, Y4, Z4, out, stream);
    }
}

// Round 17
// 121.907 us; speedup vs baseline: 1.1648x; 1.1481x over previous
//
#include <hip/hip_runtime.h>
#include <math.h>

// ---------------------------------------------------------------------------
// MultiScaleAdaptiveElasticityLossWithLame
// deformation_field: (2, 3, 160, 192, 160) f32
// image:             (2, 1, 160, 192, 160) f32
// out: scalar f32 = sum over 3 scales of mean(weight * elastic_energy)
//
// R17 scale-0 = R6's barrier-free register streamer (the only structure
// that sustained 2.38 TB/s; HBM-pattern-bound) + CX 8->10 (halo 1.25->1.2)
// + T1 bijective XCD swizzle (regime-correct: HBM-bound + inter-block halo
// and y-row reuse). launch_bounds(256,2) as proven (VGPR 120, no spill).
// Tail: R9-proven fused downsample_all8 + gather loss (verbatim).
// ---------------------------------------------------------------------------

#define LAMBDA_0 1.0f
#define MU_0 1.0f
#define KAPPA_LAMBDA 0.5f
#define KAPPA_MU 0.5f
#define BASE_WEIGHT 1.0f
#define GRADIENT_SCALING 0.1f

typedef float v4f __attribute__((ext_vector_type(4)));

constexpr int S_TY = 32;   // y rows per block tile
constexpr int S_TZ = 32;   // z per block tile (8 groups of 4)
constexpr int S_CX = 10;   // x planes per block (halo factor 1.2)

__global__ __launch_bounds__(256, 2)
void elasticity_stream_reg2s_kernel(const float* __restrict__ def,
                                    const float* __restrict__ img,
                                    int X, int Y, int Z,
                                    int nby, int nbz, int nbx,
                                    int nwg,
                                    float inv_n, float* __restrict__ out) {
    // T1: bijective XCD swizzle (nwg % 8 == 0): consecutive swizzled ids on
    // one XCD share x-halo planes and y-neighbor rows in the same L2.
    const int cpx = nwg >> 3;
    int t = (blockIdx.x % 8) * cpx + (blockIdx.x / 8);

    const int bx = t % nbx; t /= nbx;
    const int bz = t % nbz; t /= nbz;
    const int by = t % nby; t /= nby;
    const int b = t;

    const int tid = threadIdx.x;
    const int zg = tid & 7;     // 8 z-groups of 4 -> 32 z
    const int ly = tid >> 3;    // 32 y rows
    const int lane = tid & 63;
    const int laneM = (lane - 1) & 63;
    const int laneP = (lane + 1) & 63;

    const long long vol = (long long)X * Y * Z;
    const long long sX = (long long)Y * Z;
    const float* __restrict__ p0 = def + ((long long)b * 3 + 0) * vol;
    const float* __restrict__ p1 = def + ((long long)b * 3 + 1) * vol;
    const float* __restrict__ p2 = def + ((long long)b * 3 + 2) * vol;
    const float* __restrict__ p3 = img + (long long)b * vol;

    const int gy = by * S_TY + ly;
    const int gz0 = bz * S_TZ + 4 * zg;
    const int x0 = bx * S_CX;

    const long long offC  = (long long)gy * Z + gz0;
    const long long offYm = (long long)max(gy - 1, 0) * Z + gz0;
    const long long offYp = (long long)min(gy + 1, Y - 1) * Z + gz0;
    const long long offZm = offC - ((gz0 > 0) ? 1 : 0);
    const long long offZp = offC + ((gz0 + 4 < Z) ? 4 : 3);

    const bool ylo = (gy == 0), yhi = (gy == Y - 1);
    const bool zlo = (gz0 == 0), zhi = (gz0 + 4 == Z);
    const bool zem = (zg == 0),  zep = (zg == 7);

    // persistent plane-center state: 3 x 4 fields x float4 = 48 VGPR
    v4f pc[4], cc[4], nc[4];
    {
        const long long o_ = (long long)max(x0 - 1, 0) * sX;
        pc[0] = *(const v4f*)(p0 + o_ + offC);
        pc[1] = *(const v4f*)(p1 + o_ + offC);
        pc[2] = *(const v4f*)(p2 + o_ + offC);
        pc[3] = *(const v4f*)(p3 + o_ + offC);
    }
    {
        const long long o_ = (long long)x0 * sX;
        cc[0] = *(const v4f*)(p0 + o_ + offC);
        cc[1] = *(const v4f*)(p1 + o_ + offC);
        cc[2] = *(const v4f*)(p2 + o_ + offC);
        cc[3] = *(const v4f*)(p3 + o_ + offC);
    }

    float acc = 0.f;
#pragma unroll 2
    for (int i = 0; i < S_CX; ++i) {
        const int x = x0 + i;
        const bool xlo = (x == 0), xhi = (x == X - 1);
        const long long oC = (long long)x * sX;
        const long long oN = (long long)min(x + 1, X - 1) * sX;

        // next-plane centers (needed last -> issued first)
        nc[0] = *(const v4f*)(p0 + oN + offC);
        nc[1] = *(const v4f*)(p1 + oN + offC);
        nc[2] = *(const v4f*)(p2 + oN + offC);
        nc[3] = *(const v4f*)(p3 + oN + offC);

        // current-plane y neighbors (transient; L1/L2 hits of neighbor rows)
        v4f ym[4], yp[4];
        ym[0] = *(const v4f*)(p0 + oC + offYm);
        ym[1] = *(const v4f*)(p1 + oC + offYm);
        ym[2] = *(const v4f*)(p2 + oC + offYm);
        ym[3] = *(const v4f*)(p3 + oC + offYm);
        yp[0] = *(const v4f*)(p0 + oC + offYp);
        yp[1] = *(const v4f*)(p1 + oC + offYp);
        yp[2] = *(const v4f*)(p2 + oC + offYp);
        yp[3] = *(const v4f*)(p3 + oC + offYp);

        // z-halo scalars: only edge lanes of the z-tile load
        float zmS[4] = {0.f, 0.f, 0.f, 0.f};
        float zpS[4] = {0.f, 0.f, 0.f, 0.f};
        if (zem) {
            zmS[0] = p0[oC + offZm]; zmS[1] = p1[oC + offZm];
            zmS[2] = p2[oC + offZm]; zmS[3] = p3[oC + offZm];
        }
        if (zep) {
            zpS[0] = p0[oC + offZp]; zpS[1] = p1[oC + offZp];
            zpS[2] = p2[oC + offZp]; zpS[3] = p3[oC + offZp];
        }

        v4f gxA[4], gyA[4], gzA[4];
#pragma unroll
        for (int f = 0; f < 4; ++f) {
            v4f c = cc[f];
            gxA[f] = xlo ? (nc[f] - c)
                         : (xhi ? (c - pc[f]) : 0.5f * (nc[f] - pc[f]));
            gyA[f] = ylo ? (yp[f] - c)
                         : (yhi ? (c - ym[f]) : 0.5f * (yp[f] - ym[f]));
            // z+-1 from the z-neighbor lane's center registers
            float zmv = __shfl(c[3], laneM, 64);
            float zpv = __shfl(c[0], laneP, 64);
            float zm = zem ? zmS[f] : zmv;
            float zp = zep ? zpS[f] : zpv;
            v4f gz;
            gz[0] = zlo ? (c[1] - c[0]) : 0.5f * (c[1] - zm);
            gz[1] = 0.5f * (c[2] - c[0]);
            gz[2] = 0.5f * (c[3] - c[1]);
            gz[3] = zhi ? (c[3] - c[2]) : 0.5f * (zp - c[2]);
            gzA[f] = gz;
        }

#pragma unroll
        for (int j = 0; j < 4; ++j) {
            float Exx = gxA[0][j], Eyy = gyA[1][j], Ezz = gzA[2][j];
            float Exy = 0.5f * (gyA[0][j] + gxA[1][j]);
            float Exz = 0.5f * (gzA[0][j] + gxA[2][j]);
            float Eyz = 0.5f * (gzA[1][j] + gyA[2][j]);
            float tr = Exx + Eyy + Ezz;
            float g = sqrtf(gxA[3][j] * gxA[3][j] + gyA[3][j] * gyA[3][j] +
                            gzA[3][j] * gzA[3][j]);
            float lam = LAMBDA_0 + KAPPA_LAMBDA * g;
            float mu  = MU_0 + KAPPA_MU * g;
            float energy = 0.5f * lam * tr * tr +
                           mu * (Exx * Exx + Eyy * Eyy + Ezz * Ezz +
                                 2.0f * (Exy * Exy + Exz * Exz + Eyz * Eyz));
            acc += (BASE_WEIGHT + GRADIENT_SCALING * g) * energy;
        }

        // rotate centers
#pragma unroll
        for (int f = 0; f < 4; ++f) { pc[f] = cc[f]; cc[f] = nc[f]; }
    }

    float val = acc * inv_n;
    for (int off = 32; off > 0; off >>= 1)
        val += __shfl_down(val, off, 64);
    __shared__ float smem[4];
    const int wid = (int)(threadIdx.x >> 6);
    if ((threadIdx.x & 63) == 0) smem[wid] = val;
    __syncthreads();
    if (threadIdx.x == 0)
        atomicAdd(out, smem[0] + smem[1] + smem[2] + smem[3]);
}

// --------- fused downsample: all 8 maps, z-innermost (R9 verbatim) ----------
__global__ void downsample_all8_kernel(const float* __restrict__ def,
                                       const float* __restrict__ img,
                                       float* __restrict__ odef,
                                       float* __restrict__ oimg,
                                       int inX, int inY, int inZ,
                                       int outX, int outY, int outZ,
                                       float rx, float ry, float rz) {
    long long pervol = (long long)outX * outY * outZ;
    long long total = 8LL * pervol;
    long long idx = (long long)blockIdx.x * blockDim.x + threadIdx.x;
    if (idx >= total) return;

    int m = (int)(idx / pervol);
    long long r = idx % pervol;
    int z = (int)(r % outZ);
    long long t = r / outZ;
    int y = (int)(t % outY);
    int x = (int)(t / outY);

    long long invol = (long long)inX * inY * inZ;
    const float* src;
    float* dst;
    if (m < 6) { src = def + (long long)m * invol;       dst = odef + (long long)m * pervol; }
    else       { src = img + (long long)(m - 6) * invol; dst = oimg + (long long)(m - 6) * pervol; }

    float cx = (float)x * rx;
    float cy = (float)y * ry;
    float cz = (float)z * rz;
    int ix0 = (int)floorf(cx), iy0 = (int)floorf(cy), iz0 = (int)floorf(cz);
    float wx = cx - (float)ix0, wy = cy - (float)iy0, wz = cz - (float)iz0;
    int ix1 = min(ix0 + 1, inX - 1);
    int iy1 = min(iy0 + 1, inY - 1);
    int iz1 = min(iz0 + 1, inZ - 1);

    long long sYZ = (long long)inY * inZ;
    long long bx0 = (long long)ix0 * sYZ, bx1 = (long long)ix1 * sYZ;
    long long by0 = (long long)iy0 * inZ, by1 = (long long)iy1 * inZ;

    float v000 = src[bx0 + by0 + iz0], v001 = src[bx0 + by0 + iz1];
    float v010 = src[bx0 + by1 + iz0], v011 = src[bx0 + by1 + iz1];
    float v100 = src[bx1 + by0 + iz0], v101 = src[bx1 + by0 + iz1];
    float v110 = src[bx1 + by1 + iz0], v111 = src[bx1 + by1 + iz1];

    float a00 = v000 * (1.f - wx) + v100 * wx;
    float a01 = v001 * (1.f - wx) + v101 * wx;
    float a10 = v010 * (1.f - wx) + v110 * wx;
    float a11 = v011 * (1.f - wx) + v111 * wx;
    float b0 = a00 * (1.f - wy) + a10 * wy;
    float b1 = a01 * (1.f - wy) + a11 * wy;
    dst[r] = b0 * (1.f - wz) + b1 * wz;
}

// ----------------- gather loss kernel (scales 1,2; R9 verbatim) -------------
__global__ void elasticity_loss_v4_kernel(const float* __restrict__ def,
                                          const float* __restrict__ img,
                                          int B, int X, int Y, int Z,
                                          float inv_n,
                                          float* __restrict__ out) {
    const int Zg = Z >> 2;
    long long total = (long long)B * X * Y * Zg;
    long long idx = (long long)blockIdx.x * blockDim.x + threadIdx.x;
    float val = 0.f;
    if (idx < total) {
        int zg = (int)(idx % Zg);
        long long t = idx / Zg;
        int y = (int)(t % Y);
        t /= Y;
        int x = (int)(t % X);
        int b = (int)(t / X);
        int z0 = zg << 2;

        long long vol = (long long)X * Y * Z;
        const float* base0 = def + ((long long)b * 3 + 0) * vol;
        const float* base1 = def + ((long long)b * 3 + 1) * vol;
        const float* base2 = def + ((long long)b * 3 + 2) * vol;
        const float* base3 = img + (long long)b * vol;
        const float* bases[4] = {base0, base1, base2, base3};

        long long sX = (long long)Y * Z;
        long long c = (long long)x * sX + (long long)y * Z + z0;
        long long cxm = (x > 0) ? c - sX : c;
        long long cxp = (x < X - 1) ? c + sX : c;
        long long cym = (y > 0) ? c - Z : c;
        long long cyp = (y < Y - 1) ? c + Z : c;
        long long czm = (z0 > 0) ? c - 1 : c;
        long long czp = (z0 + 4 < Z) ? c + 4 : c;

        float C[4][4], XM[4][4], XP[4][4], YM[4][4], YP[4][4];
        float ZM[4], ZP[4];
#pragma unroll
        for (int f = 0; f < 4; ++f) {
            const float* p = bases[f];
            float4 tc = *(const float4*)(p + c);
            float4 txm = *(const float4*)(p + cxm);
            float4 txp = *(const float4*)(p + cxp);
            float4 tym = *(const float4*)(p + cym);
            float4 typ = *(const float4*)(p + cyp);
            ZM[f] = p[czm];
            ZP[f] = p[czp];
            C[f][0] = tc.x;  C[f][1] = tc.y;  C[f][2] = tc.z;  C[f][3] = tc.w;
            XM[f][0] = txm.x; XM[f][1] = txm.y; XM[f][2] = txm.z; XM[f][3] = txm.w;
            XP[f][0] = txp.x; XP[f][1] = txp.y; XP[f][2] = txp.z; XP[f][3] = txp.w;
            YM[f][0] = tym.x; YM[f][1] = tym.y; YM[f][2] = tym.z; YM[f][3] = tym.w;
            YP[f][0] = typ.x; YP[f][1] = typ.y; YP[f][2] = typ.z; YP[f][3] = typ.w;
        }

        const bool xlo = (x == 0), xhi = (x == X - 1);
        const bool ylo = (y == 0), yhi = (y == Y - 1);
        const bool zlo = (z0 == 0), zhi = (z0 + 4 == Z);

        float GX[4][4], GY[4][4], GZ[4][4];
#pragma unroll
        for (int f = 0; f < 4; ++f) {
#pragma unroll
            for (int i = 0; i < 4; ++i) {
                GX[f][i] = xlo ? (XP[f][i] - C[f][i])
                               : (xhi ? (C[f][i] - XM[f][i])
                                      : 0.5f * (XP[f][i] - XM[f][i]));
                GY[f][i] = ylo ? (YP[f][i] - C[f][i])
                               : (yhi ? (C[f][i] - YM[f][i])
                                      : 0.5f * (YP[f][i] - YM[f][i]));
            }
            GZ[f][0] = zlo ? (C[f][1] - C[f][0]) : 0.5f * (C[f][1] - ZM[f]);
            GZ[f][1] = 0.5f * (C[f][2] - C[f][0]);
            GZ[f][2] = 0.5f * (C[f][3] - C[f][1]);
            GZ[f][3] = zhi ? (C[f][3] - C[f][2]) : 0.5f * (ZP[f] - C[f][2]);
        }

        float acc = 0.f;
#pragma unroll
        for (int i = 0; i < 4; ++i) {
            float Exx = GX[0][i], Eyy = GY[1][i], Ezz = GZ[2][i];
            float Exy = 0.5f * (GY[0][i] + GX[1][i]);
            float Exz = 0.5f * (GZ[0][i] + GX[2][i]);
            float Eyz = 0.5f * (GZ[1][i] + GY[2][i]);
            float tr = Exx + Eyy + Ezz;
            float g = sqrtf(GX[3][i] * GX[3][i] + GY[3][i] * GY[3][i] +
                            GZ[3][i] * GZ[3][i]);
            float lam = LAMBDA_0 + KAPPA_LAMBDA * g;
            float mu  = MU_0 + KAPPA_MU * g;
            float energy = 0.5f * lam * tr * tr +
                           mu * (Exx * Exx + Eyy * Eyy + Ezz * Ezz +
                                 2.0f * (Exy * Exy + Exz * Exz + Eyz * Eyz));
            float wgt = BASE_WEIGHT + GRADIENT_SCALING * g;
            acc += wgt * energy;
        }
        val = acc * inv_n;
    }

    for (int off = 32; off > 0; off >>= 1)
        val += __shfl_down(val, off, 64);
    __shared__ float smem[8];
    int lane = threadIdx.x & 63;
    int wid = (int)(threadIdx.x >> 6);
    if (lane == 0) smem[wid] = val;
    __syncthreads();
    if (threadIdx.x == 0) {
        float s = 0.f;
        int nw = (int)(blockDim.x >> 6);
        for (int i = 0; i < nw; ++i) s += smem[i];
        atomicAdd(out, s);
    }
}

static void launch_loss_v4(const float* def, const float* img, int B, int X,
                           int Y, int Z, float* out, hipStream_t stream) {
    const int BLOCK = 256;
    long long nvox = (long long)B * X * Y * Z;
    long long total = nvox >> 2;
    float inv_n = (float)(1.0 / (double)nvox);
    int grid = (int)((total + BLOCK - 1) / BLOCK);
    elasticity_loss_v4_kernel<<<grid, BLOCK, 0, stream>>>(def, img, B, X, Y, Z,
                                                          inv_n, out);
}

extern "C" void kernel_launch(void* const* d_in, const int* in_sizes, int n_in,
                              void* d_out, int out_size, void* d_ws, size_t ws_size,
                              hipStream_t stream) {
    const float* def = (const float*)d_in[0];   // (2,3,160,192,160)
    const float* img = (const float*)d_in[1];   // (2,1,160,192,160)
    float* out = (float*)d_out;

    const int B = 2;
    const int X0 = 160, Y0 = 192, Z0 = 160;

    (void)hipMemsetAsync(out, 0, sizeof(float), stream);

    const int BLOCK = 256;

    // ---------------- scale 0: barrier-free streamer + XCD swizzle ----------
    {
        long long nvox = (long long)B * X0 * Y0 * Z0;
        float inv_n = (float)(1.0 / (double)nvox);
        int nby = Y0 / S_TY;   // 6
        int nbz = Z0 / S_TZ;   // 5
        int nbx = X0 / S_CX;   // 16
        int nwg = B * nby * nbz * nbx;   // 960 (divisible by 8)
        elasticity_stream_reg2s_kernel<<<nwg, 256, 0, stream>>>(def, img,
                                                                X0, Y0, Z0,
                                                                nby, nbz, nbx,
                                                                nwg,
                                                                inv_n, out);
    }

    // workspace layout
    const int X2 = 80, Y2 = 96, Z2 = 80;
    const int X4 = 40, Y4 = 48, Z4 = 40;
    long long vol2 = (long long)X2 * Y2 * Z2;
    long long vol4 = (long long)X4 * Y4 * Z4;

    float* def2 = (float*)d_ws;
    float* img2 = def2 + (long long)B * 3 * vol2;
    float* def4 = img2 + (long long)B * vol2;
    float* img4 = def4 + (long long)B * 3 * vol4;

    // ---------------- scale 1 (x2 downsample, fused all-8-maps) -------------
    {
        float rx = (float)((double)(X0 - 1) / (double)(X2 - 1));
        float ry = (float)((double)(Y0 - 1) / (double)(Y2 - 1));
        float rz = (float)((double)(Z0 - 1) / (double)(Z2 - 1));
        long long total = 8LL * vol2;
        int g = (int)((total + BLOCK - 1) / BLOCK);
        downsample_all8_kernel<<<g, BLOCK, 0, stream>>>(def, img, def2, img2,
                                                        X0, Y0, Z0, X2, Y2, Z2,
                                                        rx, ry, rz);
        launch_loss_v4(def2, img2, B, X2, Y2, Z2, out, stream);
    }

    // ---------------- scale 2 (x4 downsample, from original) ----------------
    {
        float rx = (float)((double)(X0 - 1) / (double)(X4 - 1));
        float ry = (float)((double)(Y0 - 1) / (double)(Y4 - 1));
        float rz = (float)((double)(Z0 - 1) / (double)(Z4 - 1));
        long long total = 8LL * vol4;
        int g = (int)((total + BLOCK - 1) / BLOCK);
        downsample_all8_kernel<<<g, BLOCK, 0, stream>>>(def, img, def4, img4,
                                                        X0, Y0, Z0, X4, Y4, Z4,
                                                        rx, ry, rz);
        launch_loss_v4(def4, img4, B, X4, Y4, Z4, out, stream);
    }
}